// Round 9
// baseline (618.033 us; speedup 1.0000x reference)
//
#include <hip/hip_runtime.h>
#include <hip/hip_bf16.h>

#define BB 8
#define SS 16
#define HH 32
#define DH 128
#define HD 4096
#define PAST 4080
#define TOT 4096
#define MM 128   // BB*SS

// d_out float offsets
#define OUT_O  0
#define ATTN_O 524288
#define K_O    17301504
#define V_O    151519232

// ws float offsets
#define QR_O 0
#define OH_O 524288          // oh (written by pv_reduce); earlier: stats (dead by then)
#define STATS_O 524288       // 4096*32*2 = 262144 floats
#define RT_O 1048576
#define PW_O 1050624         // Wo-GEMM partials; earlier: pv partials (8.4 MB)

typedef __attribute__((ext_vector_type(8))) short short8;
typedef __attribute__((ext_vector_type(4))) float f32x4;
typedef __attribute__((ext_vector_type(4))) float f4v;

static __device__ inline unsigned short f2bf(float x) {
  __hip_bfloat16 h = __float2bfloat16(x);
  return *reinterpret_cast<unsigned short*>(&h);
}
static __device__ inline short8 cvt8(float4 a, float4 b) {
  short8 v;
  v[0] = (short)f2bf(a.x); v[1] = (short)f2bf(a.y);
  v[2] = (short)f2bf(a.z); v[3] = (short)f2bf(a.w);
  v[4] = (short)f2bf(b.x); v[5] = (short)f2bf(b.y);
  v[6] = (short)f2bf(b.z); v[7] = (short)f2bf(b.w);
  return v;
}

// ------------- split-K MFMA bf16 GEMM: P[mat][ks][m][n] partials --------------
// grid 769 (QKV; block 768 builds rope table) or 256 (Wo, rt==nullptr)
#define LDP 72   // padded LDS row stride in bf16 elements (144 B)
__global__ __launch_bounds__(256) void gemm_mfma(
    const float* __restrict__ A, const float* __restrict__ W0,
    const float* __restrict__ W1, const float* __restrict__ W2,
    float* __restrict__ P, float* __restrict__ rt) {
  if (rt != nullptr && blockIdx.x == 768) {   // fused rope-table block
    int t = threadIdx.x;
#pragma unroll
    for (int i = 0; i < 4; ++i) {
      int idx = t + i * 256;          // 0..1023
      int s = idx >> 6, j = idx & 63;
      double inv = exp(-((double)(2 * j) / 128.0) * log(10000.0));
      double ang = (double)(PAST + s) * inv;
      rt[idx] = (float)cos(ang);
      rt[1024 + idx] = (float)sin(ang);
    }
    return;
  }
  int bx = blockIdx.x;
  int mat = bx >> 8;
  int rem = bx & 255;
  int nc = rem >> 3, ks = rem & 7;
  const float* Wm = (mat == 0) ? W0 : ((mat == 1) ? W1 : W2);
  int n0 = nc * 128;
  int tid = threadIdx.x;
  int lane = tid & 63, wid = tid >> 6;
  int wm = wid >> 1, wn = wid & 1;       // 2x2 wave grid, each 64x64
  int l15 = lane & 15, l4 = lane >> 4;

  __shared__ __align__(16) unsigned short As[128 * LDP];
  __shared__ __align__(16) unsigned short Bs[128 * LDP];

  f32x4 acc[4][4];
#pragma unroll
  for (int i = 0; i < 4; ++i)
#pragma unroll
    for (int j = 0; j < 4; ++j) acc[i][j] = (f32x4){0.f, 0.f, 0.f, 0.f};

  int srow = tid >> 1;                    // 0..127
  int skh = (tid & 1) * 32;               // k half within BK=64

  for (int kt = 0; kt < 8; ++kt) {
    int k0 = ks * 512 + kt * 64;
    const float* Ap = &A[(size_t)srow * 4096 + k0 + skh];
    const float* Wp = &Wm[(size_t)(n0 + srow) * 4096 + k0 + skh];
    float4 va[8], vb[8];
#pragma unroll
    for (int i = 0; i < 8; ++i) {
      va[i] = *(const float4*)(Ap + 4 * i);
      vb[i] = *(const float4*)(Wp + 4 * i);
    }
    __syncthreads();                      // prev-iter LDS reads done
    unsigned short* Asp = &As[srow * LDP + skh];
    unsigned short* Bsp = &Bs[srow * LDP + skh];
#pragma unroll
    for (int i = 0; i < 4; ++i) {
      *(short8*)(Asp + 8 * i) = cvt8(va[2 * i], va[2 * i + 1]);
      *(short8*)(Bsp + 8 * i) = cvt8(vb[2 * i], vb[2 * i + 1]);
    }
    __syncthreads();
#pragma unroll
    for (int s = 0; s < 2; ++s) {         // two K=32 steps within BK=64
      short8 af[4], bf[4];
#pragma unroll
      for (int f = 0; f < 4; ++f) {
        int ar = wm * 64 + f * 16 + l15;
        af[f] = *(const short8*)&As[ar * LDP + s * 32 + l4 * 8];
        int br = wn * 64 + f * 16 + l15;
        bf[f] = *(const short8*)&Bs[br * LDP + s * 32 + l4 * 8];
      }
#pragma unroll
      for (int i = 0; i < 4; ++i)
#pragma unroll
        for (int j = 0; j < 4; ++j)
          acc[i][j] = __builtin_amdgcn_mfma_f32_16x16x32_bf16(
              af[i], bf[j], acc[i][j], 0, 0, 0);
    }
  }

  float* Pb = P + (size_t)(mat * 8 + ks) * 524288 + n0;
#pragma unroll
  for (int i = 0; i < 4; ++i) {
#pragma unroll
    for (int j = 0; j < 4; ++j) {
      int mbase = wm * 64 + i * 16 + l4 * 4;
      int nn = wn * 64 + j * 16 + l15;
#pragma unroll
      for (int r = 0; r < 4; ++r)
        Pb[(size_t)(mbase + r) * 4096 + nn] = acc[i][j][r];
    }
  }
}

// ------------- QKV partial-reduce + bias + RoPE + scatter (float2) ------------
// grid 1536 x 256: t < 3*131072; each thread does a d2-pair
__global__ __launch_bounds__(256) void qkv_reduce(
    const float* __restrict__ P, const float* __restrict__ bq,
    const float* __restrict__ bk, const float* __restrict__ bv,
    const float* __restrict__ rt, float* __restrict__ qr,
    float* __restrict__ kout, float* __restrict__ vout) {
  int t = blockIdx.x * 256 + threadIdx.x;
  int d2 = (t & 31) * 2;
  int h = (t >> 5) & 31;
  int m = (t >> 10) & 127;
  int mat = t >> 17;
  int n1 = h * 128 + d2, n2 = n1 + 64;
  const float* bias = (mat == 0) ? bq : ((mat == 1) ? bk : bv);
  float2 v1 = *(const float2*)&bias[n1];
  float2 v2 = *(const float2*)&bias[n2];
  const float* Pm = P + (size_t)(mat * 8) * 524288 + (size_t)m * 4096;
#pragma unroll
  for (int s = 0; s < 8; ++s) {
    float2 a = *(const float2*)&Pm[(size_t)s * 524288 + n1];
    float2 b = *(const float2*)&Pm[(size_t)s * 524288 + n2];
    v1.x += a.x; v1.y += a.y;
    v2.x += b.x; v2.y += b.y;
  }
  int st = m & 15, b = m >> 4;
  int bh = b * 32 + h;
  if (mat == 2) {
    size_t dst = (size_t)(bh * TOT + PAST + st) * 128 + d2;
    *(float2*)&vout[dst] = v1;
    *(float2*)&vout[dst + 64] = v2;
  } else {
    float2 c = *(const float2*)&rt[st * 64 + d2];
    float2 sn = *(const float2*)&rt[1024 + st * 64 + d2];
    float2 o1, o2;
    o1.x = v1.x * c.x - v2.x * sn.x;  o1.y = v1.y * c.y - v2.y * sn.y;
    o2.x = v2.x * c.x + v1.x * sn.x;  o2.y = v2.y * c.y + v1.y * sn.y;
    if (mat == 0) {
      size_t dst = (size_t)(bh * 16 + st) * 128 + d2;
      *(float2*)&qr[dst] = o1;
      *(float2*)&qr[dst + 64] = o2;
    } else {
      size_t dst = (size_t)(bh * TOT + PAST + st) * 128 + d2;
      *(float2*)&kout[dst] = o1;
      *(float2*)&kout[dst + 64] = o2;
    }
  }
}

// ------------- fused K copy + MFMA QK^T + softmax stats -----------------------
// grid = 4096: bh = (bid&7)+8*((bid>>3)&31)  [XCD-pinned], kc2 = bid>>8 (2 chunks)
#define KST 136   // bf16 row stride: 272 B = 17 x 16B units
__global__ __launch_bounds__(256) void scores_mfma(
    const float* __restrict__ pastk, const float* __restrict__ qr,
    float* __restrict__ kout, float* __restrict__ attn,
    float* __restrict__ stats) {
  int bid = blockIdx.x;
  int bh = (bid & 7) + 8 * ((bid >> 3) & 31);
  int kc2 = bid >> 8;                  // 0..15
  int tid = threadIdx.x, lane = tid & 63, w = tid >> 6;
  int l15 = lane & 15, l4 = lane >> 4;

  __shared__ __align__(16) unsigned short Ks[128 * KST];
  __shared__ __align__(16) unsigned short Qs[16 * KST];
  __shared__ float sred[2][4][16];

  const f4v* pk4 = (const f4v*)pastk;
  f4v* ko4 = (f4v*)kout;

  // ---- stage Q once: 16 x 128 f32 -> bf16, coalesced ----
#pragma unroll
  for (int i = 0; i < 2; ++i) {
    int f = tid + i * 256;
    int q = f >> 5, c = f & 31;
    f4v v = *(const f4v*)&qr[(size_t)bh * 2048 + q * 128 + c * 4];
    ushort4 u;
    u.x = f2bf(v.x); u.y = f2bf(v.y); u.z = f2bf(v.z); u.w = f2bf(v.w);
    *(ushort4*)&Qs[q * KST + c * 4] = u;
  }

  for (int half = 0; half < 2; ++half) {
    int kc = kc2 * 2 + half;
    int r0 = kc * 128;
    __syncthreads();   // Ks/sred safe to overwrite; (iter 0: no-op ordering)

    // ---- stage K chunk: 128 rows x 128 d; coalesced 16B/lane; f32 copy ----
#pragma unroll
    for (int i = 0; i < 16; ++i) {
      int f = tid + i * 256;         // 0..4095
      int row = f >> 5, c = f & 31;
      int grow = r0 + row;
      size_t kidx = (size_t)(bh * TOT + grow) * 32 + c;
      f4v v;
      if (grow < PAST) {
        v = __builtin_nontemporal_load(pk4 + ((size_t)(bh * PAST + grow) * 32 + c));
        __builtin_nontemporal_store(v, ko4 + kidx);
      } else {
        v = *((const f4v*)ko4 + kidx);
      }
      ushort4 u;
      u.x = f2bf(v.x); u.y = f2bf(v.y); u.z = f2bf(v.z); u.w = f2bf(v.w);
      *(ushort4*)&Ks[row * KST + c * 4] = u;
    }
    __syncthreads();

    // ---- MFMA: wave w covers keys [w*32, w*32+32) ----
    f32x4 acc0 = (f32x4){0.f, 0.f, 0.f, 0.f};
    f32x4 acc1 = (f32x4){0.f, 0.f, 0.f, 0.f};
#pragma unroll
    for (int s = 0; s < 4; ++s) {
      short8 aq = *(const short8*)&Qs[l15 * KST + s * 32 + l4 * 8];
      short8 b0 = *(const short8*)&Ks[(w * 32 + l15) * KST + s * 32 + l4 * 8];
      short8 b1 = *(const short8*)&Ks[(w * 32 + 16 + l15) * KST + s * 32 + l4 * 8];
      acc0 = __builtin_amdgcn_mfma_f32_16x16x32_bf16(aq, b0, acc0, 0, 0, 0);
      acc1 = __builtin_amdgcn_mfma_f32_16x16x32_bf16(aq, b1, acc1, 0, 0, 0);
    }
    const float scale = 0.088388347648318447f;
    float v0[4], v1[4], mx[4], ex[4];
#pragma unroll
    for (int r = 0; r < 4; ++r) {
      v0[r] = acc0[r] * scale;
      v1[r] = acc1[r] * scale;
      int q = l4 * 4 + r;
      size_t base = (size_t)(bh * 16 + q) * 4096 + r0 + w * 32 + l15;
      attn[base] = v0[r];
      attn[base + 16] = v1[r];
      mx[r] = fmaxf(v0[r], v1[r]);
    }
#pragma unroll
    for (int r = 0; r < 4; ++r) {
#pragma unroll
      for (int off = 1; off < 16; off <<= 1)
        mx[r] = fmaxf(mx[r], __shfl_xor(mx[r], off));
      ex[r] = __expf(v0[r] - mx[r]) + __expf(v1[r] - mx[r]);
#pragma unroll
      for (int off = 1; off < 16; off <<= 1)
        ex[r] += __shfl_xor(ex[r], off);
    }
    if (l15 == 0) {
#pragma unroll
      for (int r = 0; r < 4; ++r) {
        sred[0][w][l4 * 4 + r] = mx[r];
        sred[1][w][l4 * 4 + r] = ex[r];
      }
    }
    __syncthreads();
    if (tid < 16) {
      float M = sred[0][0][tid];
#pragma unroll
      for (int ww = 1; ww < 4; ++ww) M = fmaxf(M, sred[0][ww][tid]);
      float E = 0.f;
#pragma unroll
      for (int ww = 0; ww < 4; ++ww)
        E += sred[1][ww][tid] * __expf(sred[0][ww][tid] - M);
      size_t si = ((size_t)(bh * 16 + tid) * 32 + kc) * 2;
      stats[si] = M; stats[si + 1] = E;
    }
  }
}

// ------------- fused V copy + softmax-normalize + attn@V ----------------------
// grid = 1024: bh = (bid&7)+8*((bid>>3)&31) [XCD matches scores], nc = bid>>8
__global__ __launch_bounds__(256) void pv_kernel(
    const float* __restrict__ pastv, float* __restrict__ attn,
    const float* __restrict__ stats, float* __restrict__ vout,
    float* __restrict__ pvp) {
  int bid = blockIdx.x;
  int bh = (bid & 7) + 8 * ((bid >> 3) & 31);
  int nc = bid >> 8;                   // 0..3
  int tid = threadIdx.x;
  int dq = tid & 31, rg = tid >> 5;
  __shared__ __align__(16) float red[4][16][128];   // 32 KB; atn aliases head
  float* atn = &red[0][0][0];
  __shared__ float sm[16], si[16];

  {
    int row = tid >> 4, c0 = (tid & 15) * 2;
    float4 s4 = *(const float4*)&stats[((size_t)(bh * 16 + row) * 32 + c0) * 2];
    float m = fmaxf(s4.x, s4.z);
    float e = s4.y * __expf(s4.x - m) + s4.w * __expf(s4.z - m);
#pragma unroll
    for (int off = 1; off < 16; off <<= 1) {
      float mo = __shfl_xor(m, off), eo = __shfl_xor(e, off);
      float M = fmaxf(m, mo);
      e = e * __expf(m - M) + eo * __expf(mo - M);
      m = M;
    }
    if ((tid & 15) == 0) { sm[row] = m; si[row] = 1.f / e; }
  }
  float acc[16][4];
#pragma unroll
  for (int q = 0; q < 16; ++q)
#pragma unroll
    for (int j = 0; j < 4; ++j) acc[q][j] = 0.f;

  const f4v* pv4 = (const f4v*)pastv;
  f4v* vo4 = (f4v*)vout;
  int base0 = nc * 1024;
  __syncthreads();

  for (int slab = 0; slab < 8; ++slab) {  // 128 keys per slab
    int kbase = base0 + slab * 128;
#pragma unroll
    for (int i = 0; i < 8; ++i) {
      int idx = tid + i * 256;
      int q = idx >> 7, k = idx & 127;
      size_t ai = (size_t)(bh * 16 + q) * 4096 + kbase + k;
      float p = __expf(attn[ai] - sm[q]) * si[q];
      atn[q * 128 + k] = p;
      __builtin_nontemporal_store(p, &attn[ai]);
    }
    __syncthreads();
#pragma unroll 2
    for (int it = 0; it < 16; it += 2) {
      int kk0 = it * 8 + rg, kk1 = kk0 + 8;
      int row0 = kbase + kk0, row1 = kbase + kk1;
      size_t o0 = (size_t)(bh * TOT + row0) * 32 + dq;
      size_t o1 = (size_t)(bh * TOT + row1) * 32 + dq;
      const f4v* s0 = (row0 < PAST)
          ? (pv4 + ((size_t)(bh * PAST + row0) * 32 + dq)) : (const f4v*)(vo4 + o0);
      const f4v* s1 = (row1 < PAST)
          ? (pv4 + ((size_t)(bh * PAST + row1) * 32 + dq)) : (const f4v*)(vo4 + o1);
      f4v x0 = __builtin_nontemporal_load(s0);
      f4v x1 = __builtin_nontemporal_load(s1);
      if (row0 < PAST) __builtin_nontemporal_store(x0, vo4 + o0);
      if (row1 < PAST) __builtin_nontemporal_store(x1, vo4 + o1);
#pragma unroll
      for (int q = 0; q < 16; ++q) {
        float a = atn[q * 128 + kk0];
        acc[q][0] = fmaf(a, x0.x, acc[q][0]);
        acc[q][1] = fmaf(a, x0.y, acc[q][1]);
        acc[q][2] = fmaf(a, x0.z, acc[q][2]);
        acc[q][3] = fmaf(a, x0.w, acc[q][3]);
      }
#pragma unroll
      for (int q = 0; q < 16; ++q) {
        float a = atn[q * 128 + kk1];
        acc[q][0] = fmaf(a, x1.x, acc[q][0]);
        acc[q][1] = fmaf(a, x1.y, acc[q][1]);
        acc[q][2] = fmaf(a, x1.z, acc[q][2]);
        acc[q][3] = fmaf(a, x1.w, acc[q][3]);
      }
    }
    __syncthreads();
  }
#pragma unroll
  for (int q = 0; q < 16; ++q)
#pragma unroll
    for (int j = 0; j < 4; ++j) acc[q][j] += __shfl_xor(acc[q][j], 32);
  int wid = tid >> 6;
  if ((tid & 63) < 32) {
#pragma unroll
    for (int q = 0; q < 16; ++q) {
      f4v o; o.x = acc[q][0]; o.y = acc[q][1]; o.z = acc[q][2]; o.w = acc[q][3];
      *(f4v*)&red[wid][q][dq * 4] = o;
    }
  }
  __syncthreads();
#pragma unroll
  for (int rep = 0; rep < 8; ++rep) {
    int o = tid + rep * 256;
    int q = o >> 7, dd = o & 127;
    float s = red[0][q][dd] + red[1][q][dd] + red[2][q][dd] + red[3][q][dd];
    pvp[((size_t)(bh * 4 + nc) * 16 + q) * 128 + dd] = s;
  }
}

// ------------- pv partial reduce -> oh ---------------------------------------
__global__ __launch_bounds__(256) void pv_reduce(
    const float* __restrict__ pvp, float* __restrict__ oh) {
  int t = blockIdx.x * 256 + threadIdx.x;  // < 524288
  int dd = t & 127;
  int q = (t >> 7) & 15;
  int bh = t >> 11;
  int b = bh >> 5, h = bh & 31;
  float s = 0.f;
#pragma unroll
  for (int nc = 0; nc < 4; ++nc)
    s += pvp[((size_t)(bh * 4 + nc) * 16 + q) * 128 + dd];
  oh[(size_t)(b * 16 + q) * 4096 + h * 128 + dd] = s;
}

// ------------- Wo partial-reduce + bias ---------------------------------------
__global__ __launch_bounds__(256) void out_reduce(
    const float* __restrict__ P, const float* __restrict__ bo,
    float* __restrict__ out) {
  int t = blockIdx.x * 256 + threadIdx.x;  // < 524288
  float v = bo[t & 4095];
#pragma unroll
  for (int s = 0; s < 8; ++s) v += P[(size_t)s * 524288 + t];
  out[t] = v;
}

extern "C" void kernel_launch(void* const* d_in, const int* in_sizes, int n_in,
                              void* d_out, int out_size, void* d_ws, size_t ws_size,
                              hipStream_t stream) {
  const float* x     = (const float*)d_in[0];
  const float* pastk = (const float*)d_in[1];
  const float* pastv = (const float*)d_in[2];
  const float* Wq = (const float*)d_in[3];
  const float* bq = (const float*)d_in[4];
  const float* Wk = (const float*)d_in[5];
  const float* bk = (const float*)d_in[6];
  const float* Wv = (const float*)d_in[7];
  const float* bv = (const float*)d_in[8];
  const float* Wo = (const float*)d_in[9];
  const float* bo = (const float*)d_in[10];

  float* out  = (float*)d_out;
  float* attn = out + ATTN_O;
  float* kout = out + K_O;
  float* vout = out + V_O;

  float* ws = (float*)d_ws;
  float* qr    = ws + QR_O;
  float* oh    = ws + OH_O;
  float* stats = ws + STATS_O;   // dead before pv_reduce writes oh
  float* rt    = ws + RT_O;
  float* pw    = ws + PW_O;      // Wo partials; earlier: pv partials

  gemm_mfma<<<769, 256, 0, stream>>>(x, Wq, Wk, Wv, attn, rt);
  qkv_reduce<<<1536, 256, 0, stream>>>(attn, bq, bk, bv, rt, qr, kout, vout);
  scores_mfma<<<4096, 256, 0, stream>>>(pastk, qr, kout, attn, stats);
  pv_kernel<<<1024, 256, 0, stream>>>(pastv, attn, stats, vout, pw);
  pv_reduce<<<2048, 256, 0, stream>>>(pw, oh);
  gemm_mfma<<<256, 256, 0, stream>>>(oh, Wo, Wo, Wo, pw, nullptr);
  out_reduce<<<2048, 256, 0, stream>>>(pw, bo, out);
}

// Round 10
// 596.204 us; speedup vs baseline: 1.0366x; 1.0366x over previous
//
#include <hip/hip_runtime.h>
#include <hip/hip_bf16.h>

#define BB 8
#define SS 16
#define HH 32
#define DH 128
#define HD 4096
#define PAST 4080
#define TOT 4096
#define MM 128   // BB*SS

// d_out float offsets
#define OUT_O  0
#define ATTN_O 524288
#define K_O    17301504
#define V_O    151519232

// ws float offsets
#define QR_O 0
#define OH_O 524288          // oh (written by pv_reduce); earlier: stats (dead by then)
#define STATS_O 524288       // 4096*32*2 = 262144 floats
#define RT_O 1048576
#define PW_O 1050624         // Wo-GEMM partials; earlier: pv partials (8.4 MB)

typedef __attribute__((ext_vector_type(8))) short short8;
typedef __attribute__((ext_vector_type(4))) float f32x4;
typedef __attribute__((ext_vector_type(4))) float f4v;

static __device__ inline unsigned short f2bf(float x) {
  __hip_bfloat16 h = __float2bfloat16(x);
  return *reinterpret_cast<unsigned short*>(&h);
}
static __device__ inline short8 cvt8(float4 a, float4 b) {
  short8 v;
  v[0] = (short)f2bf(a.x); v[1] = (short)f2bf(a.y);
  v[2] = (short)f2bf(a.z); v[3] = (short)f2bf(a.w);
  v[4] = (short)f2bf(b.x); v[5] = (short)f2bf(b.y);
  v[6] = (short)f2bf(b.z); v[7] = (short)f2bf(b.w);
  return v;
}

// ------------- split-K MFMA bf16 GEMM: P[mat][ks][m][n] partials --------------
// grid 769 (QKV; block 768 builds rope table) or 256 (Wo, rt==nullptr)
#define LDP 72   // padded LDS row stride in bf16 elements (144 B)
__global__ __launch_bounds__(256) void gemm_mfma(
    const float* __restrict__ A, const float* __restrict__ W0,
    const float* __restrict__ W1, const float* __restrict__ W2,
    float* __restrict__ P, float* __restrict__ rt) {
  if (rt != nullptr && blockIdx.x == 768) {   // fused rope-table block
    int t = threadIdx.x;
#pragma unroll
    for (int i = 0; i < 4; ++i) {
      int idx = t + i * 256;          // 0..1023
      int s = idx >> 6, j = idx & 63;
      double inv = exp(-((double)(2 * j) / 128.0) * log(10000.0));
      double ang = (double)(PAST + s) * inv;
      rt[idx] = (float)cos(ang);
      rt[1024 + idx] = (float)sin(ang);
    }
    return;
  }
  int bx = blockIdx.x;
  int mat = bx >> 8;
  int rem = bx & 255;
  int nc = rem >> 3, ks = rem & 7;
  const float* Wm = (mat == 0) ? W0 : ((mat == 1) ? W1 : W2);
  int n0 = nc * 128;
  int tid = threadIdx.x;
  int lane = tid & 63, wid = tid >> 6;
  int wm = wid >> 1, wn = wid & 1;       // 2x2 wave grid, each 64x64
  int l15 = lane & 15, l4 = lane >> 4;

  __shared__ __align__(16) unsigned short As[128 * LDP];
  __shared__ __align__(16) unsigned short Bs[128 * LDP];

  f32x4 acc[4][4];
#pragma unroll
  for (int i = 0; i < 4; ++i)
#pragma unroll
    for (int j = 0; j < 4; ++j) acc[i][j] = (f32x4){0.f, 0.f, 0.f, 0.f};

  int srow = tid >> 1;                    // 0..127
  int skh = (tid & 1) * 32;               // k half within BK=64

  for (int kt = 0; kt < 8; ++kt) {
    int k0 = ks * 512 + kt * 64;
    const float* Ap = &A[(size_t)srow * 4096 + k0 + skh];
    const float* Wp = &Wm[(size_t)(n0 + srow) * 4096 + k0 + skh];
    float4 va[8], vb[8];
#pragma unroll
    for (int i = 0; i < 8; ++i) {
      va[i] = *(const float4*)(Ap + 4 * i);
      vb[i] = *(const float4*)(Wp + 4 * i);
    }
    __syncthreads();                      // prev-iter LDS reads done
    unsigned short* Asp = &As[srow * LDP + skh];
    unsigned short* Bsp = &Bs[srow * LDP + skh];
#pragma unroll
    for (int i = 0; i < 4; ++i) {
      *(short8*)(Asp + 8 * i) = cvt8(va[2 * i], va[2 * i + 1]);
      *(short8*)(Bsp + 8 * i) = cvt8(vb[2 * i], vb[2 * i + 1]);
    }
    __syncthreads();
#pragma unroll
    for (int s = 0; s < 2; ++s) {         // two K=32 steps within BK=64
      short8 af[4], bf[4];
#pragma unroll
      for (int f = 0; f < 4; ++f) {
        int ar = wm * 64 + f * 16 + l15;
        af[f] = *(const short8*)&As[ar * LDP + s * 32 + l4 * 8];
        int br = wn * 64 + f * 16 + l15;
        bf[f] = *(const short8*)&Bs[br * LDP + s * 32 + l4 * 8];
      }
#pragma unroll
      for (int i = 0; i < 4; ++i)
#pragma unroll
        for (int j = 0; j < 4; ++j)
          acc[i][j] = __builtin_amdgcn_mfma_f32_16x16x32_bf16(
              af[i], bf[j], acc[i][j], 0, 0, 0);
    }
  }

  float* Pb = P + (size_t)(mat * 8 + ks) * 524288 + n0;
#pragma unroll
  for (int i = 0; i < 4; ++i) {
#pragma unroll
    for (int j = 0; j < 4; ++j) {
      int mbase = wm * 64 + i * 16 + l4 * 4;
      int nn = wn * 64 + j * 16 + l15;
#pragma unroll
      for (int r = 0; r < 4; ++r)
        Pb[(size_t)(mbase + r) * 4096 + nn] = acc[i][j][r];
    }
  }
}

// ------------- QKV partial-reduce + bias + RoPE + scatter ---------------------
__global__ __launch_bounds__(256) void qkv_reduce(
    const float* __restrict__ P, const float* __restrict__ bq,
    const float* __restrict__ bk, const float* __restrict__ bv,
    const float* __restrict__ rt, float* __restrict__ qr,
    float* __restrict__ kout, float* __restrict__ vout) {
  int t = blockIdx.x * 256 + threadIdx.x;   // < 3*2^18
  int d2 = t & 63;
  int h = (t >> 6) & 31;
  int m = (t >> 11) & 127;
  int mat = t >> 18;
  int n1 = h * 128 + d2, n2 = n1 + 64;
  const float* bias = (mat == 0) ? bq : ((mat == 1) ? bk : bv);
  float v1 = bias[n1], v2 = bias[n2];
  const float* Pm = P + (size_t)(mat * 8) * 524288 + (size_t)m * 4096;
#pragma unroll
  for (int s = 0; s < 8; ++s) {
    v1 += Pm[(size_t)s * 524288 + n1];
    v2 += Pm[(size_t)s * 524288 + n2];
  }
  int st = m & 15, b = m >> 4;
  int bh = b * 32 + h;
  if (mat == 2) {
    size_t dst = (size_t)(bh * TOT + PAST + st) * 128;
    vout[dst + d2] = v1; vout[dst + 64 + d2] = v2;
  } else {
    float c = rt[st * 64 + d2], sn = rt[1024 + st * 64 + d2];
    float o1 = v1 * c - v2 * sn;
    float o2 = v2 * c + v1 * sn;
    if (mat == 0) {
      size_t dst = (size_t)(bh * 16 + st) * 128;
      qr[dst + d2] = o1; qr[dst + 64 + d2] = o2;
    } else {
      size_t dst = (size_t)(bh * TOT + PAST + st) * 128;
      kout[dst + d2] = o1; kout[dst + 64 + d2] = o2;
    }
  }
}

// ------------- fused K copy + MFMA QK^T + softmax stats -----------------------
// grid = 256 bh * 32 kchunks of 128 keys; 256 threads (4 waves)
#define KST 136   // bf16 row stride: 272 B = 17 x 16B units
__global__ __launch_bounds__(256) void scores_mfma(
    const float* __restrict__ pastk, const float* __restrict__ qr,
    float* __restrict__ kout, float* __restrict__ attn,
    float* __restrict__ stats) {
  int bh = blockIdx.x >> 5, kc = blockIdx.x & 31;
  int r0 = kc * 128;
  int tid = threadIdx.x, lane = tid & 63, w = tid >> 6;
  int l15 = lane & 15, l4 = lane >> 4;

  __shared__ __align__(16) unsigned short Ks[128 * KST];
  __shared__ __align__(16) unsigned short Qs[16 * KST];
  __shared__ float sred[2][4][16];

  const f4v* pk4 = (const f4v*)pastk;
  f4v* ko4 = (f4v*)kout;

#pragma unroll
  for (int i = 0; i < 16; ++i) {
    int f = tid + i * 256;         // 0..4095
    int row = f >> 5, c = f & 31;
    int grow = r0 + row;
    size_t kidx = (size_t)(bh * TOT + grow) * 32 + c;
    f4v v;
    if (grow < PAST) {
      v = __builtin_nontemporal_load(pk4 + ((size_t)(bh * PAST + grow) * 32 + c));
      __builtin_nontemporal_store(v, ko4 + kidx);
    } else {
      v = *((const f4v*)ko4 + kidx);
    }
    ushort4 u;
    u.x = f2bf(v.x); u.y = f2bf(v.y); u.z = f2bf(v.z); u.w = f2bf(v.w);
    *(ushort4*)&Ks[row * KST + c * 4] = u;
  }
#pragma unroll
  for (int i = 0; i < 2; ++i) {
    int f = tid + i * 256;
    int q = f >> 5, c = f & 31;
    f4v v = *(const f4v*)&qr[(size_t)bh * 2048 + q * 128 + c * 4];
    ushort4 u;
    u.x = f2bf(v.x); u.y = f2bf(v.y); u.z = f2bf(v.z); u.w = f2bf(v.w);
    *(ushort4*)&Qs[q * KST + c * 4] = u;
  }
  __syncthreads();

  f32x4 acc0 = (f32x4){0.f, 0.f, 0.f, 0.f};
  f32x4 acc1 = (f32x4){0.f, 0.f, 0.f, 0.f};
#pragma unroll
  for (int s = 0; s < 4; ++s) {
    short8 aq = *(const short8*)&Qs[l15 * KST + s * 32 + l4 * 8];
    short8 b0 = *(const short8*)&Ks[(w * 32 + l15) * KST + s * 32 + l4 * 8];
    short8 b1 = *(const short8*)&Ks[(w * 32 + 16 + l15) * KST + s * 32 + l4 * 8];
    acc0 = __builtin_amdgcn_mfma_f32_16x16x32_bf16(aq, b0, acc0, 0, 0, 0);
    acc1 = __builtin_amdgcn_mfma_f32_16x16x32_bf16(aq, b1, acc1, 0, 0, 0);
  }
  const float scale = 0.088388347648318447f;
  float v0[4], v1[4], mx[4], ex[4];
#pragma unroll
  for (int r = 0; r < 4; ++r) {
    v0[r] = acc0[r] * scale;
    v1[r] = acc1[r] * scale;
    int q = l4 * 4 + r;
    size_t base = (size_t)(bh * 16 + q) * 4096 + r0 + w * 32 + l15;
    attn[base] = v0[r];
    attn[base + 16] = v1[r];
    mx[r] = fmaxf(v0[r], v1[r]);
  }
#pragma unroll
  for (int r = 0; r < 4; ++r) {
#pragma unroll
    for (int off = 1; off < 16; off <<= 1)
      mx[r] = fmaxf(mx[r], __shfl_xor(mx[r], off));
    ex[r] = __expf(v0[r] - mx[r]) + __expf(v1[r] - mx[r]);
#pragma unroll
    for (int off = 1; off < 16; off <<= 1)
      ex[r] += __shfl_xor(ex[r], off);
  }
  if (l15 == 0) {
#pragma unroll
    for (int r = 0; r < 4; ++r) {
      sred[0][w][l4 * 4 + r] = mx[r];
      sred[1][w][l4 * 4 + r] = ex[r];
    }
  }
  __syncthreads();
  if (tid < 16) {
    float M = sred[0][0][tid];
#pragma unroll
    for (int ww = 1; ww < 4; ++ww) M = fmaxf(M, sred[0][ww][tid]);
    float E = 0.f;
#pragma unroll
    for (int ww = 0; ww < 4; ++ww)
      E += sred[1][ww][tid] * __expf(sred[0][ww][tid] - M);
    size_t si = ((size_t)(bh * 16 + tid) * 32 + kc) * 2;
    stats[si] = M; stats[si + 1] = E;
  }
}

// ------------- fused V copy + softmax-normalize + attn@V ----------------------
// grid = 256 bh * 4 chunks of 1024 keys; 256 threads; all blocks co-resident
__global__ __launch_bounds__(256) void pv_kernel(
    const float* __restrict__ pastv, float* __restrict__ attn,
    const float* __restrict__ stats, float* __restrict__ vout,
    float* __restrict__ pvp) {
  int blk = blockIdx.x;
  int bh = blk >> 2, nc = blk & 3;
  int tid = threadIdx.x;
  int dq = tid & 31, rg = tid >> 5;
  __shared__ __align__(16) float red[4][16][128];   // 32 KB; atn aliases head
  float* atn = &red[0][0][0];
  __shared__ float sm[16], si[16];

  {
    int row = tid >> 4, c0 = (tid & 15) * 2;
    float4 s4 = *(const float4*)&stats[((size_t)(bh * 16 + row) * 32 + c0) * 2];
    float m = fmaxf(s4.x, s4.z);
    float e = s4.y * __expf(s4.x - m) + s4.w * __expf(s4.z - m);
#pragma unroll
    for (int off = 1; off < 16; off <<= 1) {
      float mo = __shfl_xor(m, off), eo = __shfl_xor(e, off);
      float M = fmaxf(m, mo);
      e = e * __expf(m - M) + eo * __expf(mo - M);
      m = M;
    }
    if ((tid & 15) == 0) { sm[row] = m; si[row] = 1.f / e; }
  }
  float acc[16][4];
#pragma unroll
  for (int q = 0; q < 16; ++q)
#pragma unroll
    for (int j = 0; j < 4; ++j) acc[q][j] = 0.f;

  const f4v* pv4 = (const f4v*)pastv;
  f4v* vo4 = (f4v*)vout;
  int base0 = nc * 1024;
  __syncthreads();

  for (int slab = 0; slab < 8; ++slab) {  // 128 keys per slab
    int kbase = base0 + slab * 128;
#pragma unroll
    for (int i = 0; i < 8; ++i) {
      int idx = tid + i * 256;
      int q = idx >> 7, k = idx & 127;
      size_t ai = (size_t)(bh * 16 + q) * 4096 + kbase + k;
      float p = __expf(attn[ai] - sm[q]) * si[q];
      atn[q * 128 + k] = p;
      __builtin_nontemporal_store(p, &attn[ai]);
    }
    __syncthreads();
#pragma unroll 2
    for (int it = 0; it < 16; it += 2) {
      int kk0 = it * 8 + rg, kk1 = kk0 + 8;
      int row0 = kbase + kk0, row1 = kbase + kk1;
      size_t o0 = (size_t)(bh * TOT + row0) * 32 + dq;
      size_t o1 = (size_t)(bh * TOT + row1) * 32 + dq;
      const f4v* s0 = (row0 < PAST)
          ? (pv4 + ((size_t)(bh * PAST + row0) * 32 + dq)) : (const f4v*)(vo4 + o0);
      const f4v* s1 = (row1 < PAST)
          ? (pv4 + ((size_t)(bh * PAST + row1) * 32 + dq)) : (const f4v*)(vo4 + o1);
      f4v x0 = __builtin_nontemporal_load(s0);
      f4v x1 = __builtin_nontemporal_load(s1);
      if (row0 < PAST) __builtin_nontemporal_store(x0, vo4 + o0);
      if (row1 < PAST) __builtin_nontemporal_store(x1, vo4 + o1);
#pragma unroll
      for (int q = 0; q < 16; ++q) {
        float a = atn[q * 128 + kk0];
        acc[q][0] = fmaf(a, x0.x, acc[q][0]);
        acc[q][1] = fmaf(a, x0.y, acc[q][1]);
        acc[q][2] = fmaf(a, x0.z, acc[q][2]);
        acc[q][3] = fmaf(a, x0.w, acc[q][3]);
      }
#pragma unroll
      for (int q = 0; q < 16; ++q) {
        float a = atn[q * 128 + kk1];
        acc[q][0] = fmaf(a, x1.x, acc[q][0]);
        acc[q][1] = fmaf(a, x1.y, acc[q][1]);
        acc[q][2] = fmaf(a, x1.z, acc[q][2]);
        acc[q][3] = fmaf(a, x1.w, acc[q][3]);
      }
    }
    __syncthreads();
  }
#pragma unroll
  for (int q = 0; q < 16; ++q)
#pragma unroll
    for (int j = 0; j < 4; ++j) acc[q][j] += __shfl_xor(acc[q][j], 32);
  int wid = tid >> 6;
  if ((tid & 63) < 32) {
#pragma unroll
    for (int q = 0; q < 16; ++q) {
      f4v o; o.x = acc[q][0]; o.y = acc[q][1]; o.z = acc[q][2]; o.w = acc[q][3];
      *(f4v*)&red[wid][q][dq * 4] = o;
    }
  }
  __syncthreads();
#pragma unroll
  for (int rep = 0; rep < 8; ++rep) {
    int o = tid + rep * 256;
    int q = o >> 7, dd = o & 127;
    float s = red[0][q][dd] + red[1][q][dd] + red[2][q][dd] + red[3][q][dd];
    pvp[((size_t)(bh * 4 + nc) * 16 + q) * 128 + dd] = s;
  }
}

// ------------- pv partial reduce -> oh ---------------------------------------
__global__ __launch_bounds__(256) void pv_reduce(
    const float* __restrict__ pvp, float* __restrict__ oh) {
  int t = blockIdx.x * 256 + threadIdx.x;  // < 524288
  int dd = t & 127;
  int q = (t >> 7) & 15;
  int bh = t >> 11;
  int b = bh >> 5, h = bh & 31;
  float s = 0.f;
#pragma unroll
  for (int nc = 0; nc < 4; ++nc)
    s += pvp[((size_t)(bh * 4 + nc) * 16 + q) * 128 + dd];
  oh[(size_t)(b * 16 + q) * 4096 + h * 128 + dd] = s;
}

// ------------- Wo partial-reduce + bias ---------------------------------------
__global__ __launch_bounds__(256) void out_reduce(
    const float* __restrict__ P, const float* __restrict__ bo,
    float* __restrict__ out) {
  int t = blockIdx.x * 256 + threadIdx.x;  // < 524288
  float v = bo[t & 4095];
#pragma unroll
  for (int s = 0; s < 8; ++s) v += P[(size_t)s * 524288 + t];
  out[t] = v;
}

extern "C" void kernel_launch(void* const* d_in, const int* in_sizes, int n_in,
                              void* d_out, int out_size, void* d_ws, size_t ws_size,
                              hipStream_t stream) {
  const float* x     = (const float*)d_in[0];
  const float* pastk = (const float*)d_in[1];
  const float* pastv = (const float*)d_in[2];
  const float* Wq = (const float*)d_in[3];
  const float* bq = (const float*)d_in[4];
  const float* Wk = (const float*)d_in[5];
  const float* bk = (const float*)d_in[6];
  const float* Wv = (const float*)d_in[7];
  const float* bv = (const float*)d_in[8];
  const float* Wo = (const float*)d_in[9];
  const float* bo = (const float*)d_in[10];

  float* out  = (float*)d_out;
  float* attn = out + ATTN_O;
  float* kout = out + K_O;
  float* vout = out + V_O;

  float* ws = (float*)d_ws;
  float* qr    = ws + QR_O;
  float* oh    = ws + OH_O;
  float* stats = ws + STATS_O;   // dead before pv_reduce writes oh
  float* rt    = ws + RT_O;
  float* pw    = ws + PW_O;      // Wo partials; earlier: pv partials

  gemm_mfma<<<769, 256, 0, stream>>>(x, Wq, Wk, Wv, attn, rt);
  qkv_reduce<<<3072, 256, 0, stream>>>(attn, bq, bk, bv, rt, qr, kout, vout);
  scores_mfma<<<8192, 256, 0, stream>>>(pastk, qr, kout, attn, stats);
  pv_kernel<<<1024, 256, 0, stream>>>(pastv, attn, stats, vout, pw);
  pv_reduce<<<2048, 256, 0, stream>>>(pw, oh);
  gemm_mfma<<<256, 256, 0, stream>>>(oh, Wo, Wo, Wo, pw, nullptr);
  out_reduce<<<2048, 256, 0, stream>>>(pw, bo, out);
}